// Round 2
// baseline (245.182 us; speedup 1.0000x reference)
//
#include <hip/hip_runtime.h>
#include <math.h>

// PatchNorm forward (training-mode Welford update + normalize), single-pass.
// Shapes (fixed by the reference setup):
//   patches (B=32, S=1024, D=768) fp32, N = B*S = 32768 tokens
//   pos_h/pos_w/key_pad_mask (B,S) int32
//   n (32,32) fp32, mean/m2 (32,32,256) fp32
//   out (B,S,768) fp32
//
// Key identity (n_g is uniform within a grid cell):
//   sum(delta)/n_g          = (S1 - cnt*mo)/n_g,          S1 = sum w*xbar
//   sum(delta*delta2)       = S2 - (mo+mn)*S1 + cnt*mo*mn, S2 = sum w*xbar^2
// so ONE scatter pass over patches suffices (no xbar buffer, no 2nd/3rd pass).

#define EPSF 1e-6f

static constexpr int W_GRID = 32;   // grid width (pf = pos_h*W + pos_w)
static constexpr int P2     = 256;  // patch_res^2
static constexpr int P4     = 64;   // P2/4  (float4 units per cell row)
static constexpr int D4     = 192;  // D/4   (float4 units per token)

// ---- kernel 0: zero the atomic accumulators (counts + S1 + S2) -------------
__global__ void k_zero(float4* __restrict__ buf, int n4) {
    int q = blockIdx.x * blockDim.x + threadIdx.x;
    if (q < n4) buf[q] = make_float4(0.f, 0.f, 0.f, 0.f);
}

// ---- kernel 1: fused channel-mean + moment scatter -------------------------
// 1 wave per token; lane l handles float4 chunk l of the 256-wide cell row.
__global__ void k_accum(const float4* __restrict__ patches4,
                        const int* __restrict__ pos_h,
                        const int* __restrict__ pos_w,
                        const int* __restrict__ mask,
                        float* __restrict__ counts,
                        float* __restrict__ S1,
                        float* __restrict__ S2) {
    const int wave = threadIdx.x >> 6;
    const int lane = threadIdx.x & 63;
    const int i = blockIdx.x * 4 + wave;          // token index
    if (mask[i] != 0) return;                     // padded: contributes nothing
    const int g = pos_h[i] * W_GRID + pos_w[i];

    const float4* tp = patches4 + (size_t)i * D4;
    float4 a = tp[lane];
    float4 b = tp[lane + P4];
    float4 c = tp[lane + 2 * P4];
    float4 xb;
    xb.x = (a.x + b.x + c.x) * (1.0f / 3.0f);
    xb.y = (a.y + b.y + c.y) * (1.0f / 3.0f);
    xb.z = (a.z + b.z + c.z) * (1.0f / 3.0f);
    xb.w = (a.w + b.w + c.w) * (1.0f / 3.0f);

    float* s1 = S1 + g * P2 + 4 * lane;
    float* s2 = S2 + g * P2 + 4 * lane;
    atomicAdd(s1 + 0, xb.x);  atomicAdd(s2 + 0, xb.x * xb.x);
    atomicAdd(s1 + 1, xb.y);  atomicAdd(s2 + 1, xb.y * xb.y);
    atomicAdd(s1 + 2, xb.z);  atomicAdd(s2 + 2, xb.z * xb.z);
    atomicAdd(s1 + 3, xb.w);  atomicAdd(s2 + 3, xb.w * xb.w);
    if (lane == 0) atomicAdd(&counts[g], 1.0f);
}

// ---- kernel 2: per-(cell,p) closed-form stats ------------------------------
__global__ void k_stats(const float* __restrict__ n_old,
                        const float* __restrict__ mean_old,
                        const float* __restrict__ m2_old,
                        const float* __restrict__ counts,
                        const float* __restrict__ S1,
                        const float* __restrict__ S2,
                        float* __restrict__ mean_new,
                        float* __restrict__ inv_std,
                        int HWP2) {
    int j = blockIdx.x * blockDim.x + threadIdx.x;
    if (j >= HWP2) return;
    int g = j >> 8;                               // j / P2
    float cnt = counts[g];
    float nn  = n_old[g] + cnt;
    float ng  = fmaxf(nn, 1.0f);
    float mo  = mean_old[j];
    float s1  = S1[j];
    float s2  = S2[j];
    float mn  = mo + (s1 - cnt * mo) / ng;
    float m2n = m2_old[j] + (s2 - (mo + mn) * s1 + cnt * mo * mn);
    float var = (nn < 2.0f) ? 1.0f : (m2n / ng);
    mean_new[j] = mn;
    inv_std[j]  = 1.0f / (sqrtf(var) + EPSF);
}

// ---- kernel 3: normalize ----------------------------------------------------
// 192 threads (3 waves) per token; thread t handles float4 chunk t.
__global__ void k_norm(const float4* __restrict__ patches4,
                       const int* __restrict__ pos_h,
                       const int* __restrict__ pos_w,
                       const int* __restrict__ mask,
                       const float4* __restrict__ mean_new4,
                       const float4* __restrict__ inv_std4,
                       float4* __restrict__ out4) {
    const int i = blockIdx.x;
    const int t = threadIdx.x;                    // 0..191
    const int p4 = t & 63;                        // float4 index within cell row
    const int g = pos_h[i] * W_GRID + pos_w[i];
    const float wv = (mask[i] == 0) ? 1.0f : 0.0f;

    float4 x = patches4[(size_t)i * D4 + t];
    float4 m = mean_new4[g * P4 + p4];
    float4 s = inv_std4[g * P4 + p4];
    float4 o;
    o.x = (x.x - m.x) * s.x * wv;
    o.y = (x.y - m.y) * s.y * wv;
    o.z = (x.z - m.z) * s.z * wv;
    o.w = (x.w - m.w) * s.w * wv;
    out4[(size_t)i * D4 + t] = o;
}

extern "C" void kernel_launch(void* const* d_in, const int* in_sizes, int n_in,
                              void* d_out, int out_size, void* d_ws, size_t ws_size,
                              hipStream_t stream) {
    const float* patches = (const float*)d_in[0];
    const int*   pos_h   = (const int*)d_in[1];
    const int*   pos_w   = (const int*)d_in[2];
    const int*   mask    = (const int*)d_in[3];
    const float* n_old   = (const float*)d_in[4];
    const float* mean    = (const float*)d_in[5];
    const float* m2      = (const float*)d_in[6];
    float* out = (float*)d_out;

    const int N    = in_sizes[1];   // 32768 tokens
    const int HW   = in_sizes[4];   // 1024 grid cells
    const int HWP2 = in_sizes[5];   // 262144

    // workspace layout (floats):
    //   [counts HW][S1 HWP2][S2 HWP2]   <- zeroed each call (atomics)
    //   [mean_new HWP2][inv_std HWP2]
    float* ws       = (float*)d_ws;
    float* counts   = ws;
    float* S1       = counts + HW;
    float* S2       = S1 + HWP2;
    float* mean_new = S2 + HWP2;
    float* inv_std  = mean_new + HWP2;

    const int zero_floats = HW + 2 * HWP2;        // contiguous region
    const int zero4 = zero_floats / 4;
    k_zero<<<(zero4 + 255) / 256, 256, 0, stream>>>((float4*)d_ws, zero4);

    k_accum<<<N / 4, 256, 0, stream>>>((const float4*)patches, pos_h, pos_w, mask,
                                       counts, S1, S2);
    k_stats<<<(HWP2 + 255) / 256, 256, 0, stream>>>(n_old, mean, m2, counts, S1, S2,
                                                    mean_new, inv_std, HWP2);
    k_norm<<<N, 192, 0, stream>>>((const float4*)patches, pos_h, pos_w, mask,
                                  (const float4*)mean_new, (const float4*)inv_std,
                                  (float4*)out);
}

// Round 3
// 79.748 us; speedup vs baseline: 3.0745x; 3.0745x over previous
//
#include <hip/hip_runtime.h>
#include <math.h>

// PatchNorm forward (training-mode Welford update + normalize).
// Scatter→gather restructure: CSR token lists per grid cell, then one block
// per cell reduces its tokens without any fp atomics.
//
// Shapes (fixed by the reference setup):
//   patches (B=32, S=1024, D=768) fp32, N = B*S = 32768 tokens
//   pos_h/pos_w/key_pad_mask (B,S) int32
//   n (32,32) fp32, mean/m2 (32,32,256) fp32,  out (B,S,768) fp32
//
// Closed-form per-cell moments (n_g uniform within a cell):
//   mean_new = mo + (S1 - cnt*mo)/n_g                 S1 = sum_valid xbar
//   m2_new   = m2 + S2 - (mo+mn)*S1 + cnt*mo*mn       S2 = sum_valid xbar^2

#define EPSF 1e-6f

static constexpr int W_GRID = 32;   // grid width (pf = pos_h*W + pos_w)
static constexpr int P2     = 256;  // patch_res^2
static constexpr int P4     = 64;   // P2/4  (float4 units per cell row)
static constexpr int D4     = 192;  // D/4   (float4 units per token)

// ---- kernel A0: zero the int counters (cnt + fill) -------------------------
__global__ void k_zero_cnt(int* __restrict__ buf, int n) {
    int t = blockIdx.x * blockDim.x + threadIdx.x;
    if (t < n) buf[t] = 0;
}

// ---- kernel A1: pf per token + per-cell count ------------------------------
__global__ void k_count(const int* __restrict__ pos_h,
                        const int* __restrict__ pos_w,
                        const int* __restrict__ mask,
                        int* __restrict__ pf,
                        int* __restrict__ cnt, int N) {
    int i = blockIdx.x * blockDim.x + threadIdx.x;
    if (i >= N) return;
    int valid = (mask[i] == 0);
    int g = valid ? (pos_h[i] * W_GRID + pos_w[i]) : -1;
    pf[i] = g;
    if (valid) atomicAdd(&cnt[g], 1);
}

// ---- kernel A2: exclusive prefix scan over HW=1024 cells (single block) ----
__global__ void k_scan(const int* __restrict__ cnt,
                       int* __restrict__ offs, int HW) {
    __shared__ int buf[2][1024];
    int t = threadIdx.x;
    buf[0][t] = (t < HW) ? cnt[t] : 0;
    __syncthreads();
    int src = 0;
    for (int d = 1; d < 1024; d <<= 1) {
        int v = buf[src][t];
        if (t >= d) v += buf[src][t - d];
        buf[src ^ 1][t] = v;
        src ^= 1;
        __syncthreads();
    }
    if (t < HW) offs[t + 1] = buf[src][t];
    if (t == 0) offs[0] = 0;
}

// ---- kernel A3: fill CSR token lists ---------------------------------------
__global__ void k_fill(const int* __restrict__ pf,
                       const int* __restrict__ offs,
                       int* __restrict__ fill,
                       int* __restrict__ list, int N) {
    int i = blockIdx.x * blockDim.x + threadIdx.x;
    if (i >= N) return;
    int g = pf[i];
    if (g < 0) return;
    int slot = atomicAdd(&fill[g], 1);
    list[offs[g] + slot] = i;
}

// ---- kernel B: per-cell gather of moments + fused stats --------------------
// One block (256 threads = 4 waves) per grid cell. Wave w handles tokens
// list[beg+w], list[beg+w+4], ...; lane l owns p = 4l..4l+3.
__global__ void k_moments(const float4* __restrict__ patches4,
                          const int* __restrict__ list,
                          const int* __restrict__ offs,
                          const float* __restrict__ n_old,
                          const float* __restrict__ mean_old,
                          const float* __restrict__ m2_old,
                          float* __restrict__ mean_new,
                          float* __restrict__ inv_std) {
    const int g    = blockIdx.x;
    const int wave = threadIdx.x >> 6;
    const int lane = threadIdx.x & 63;
    const int beg  = offs[g], end = offs[g + 1];

    float4 s1 = make_float4(0.f, 0.f, 0.f, 0.f);
    float4 s2 = make_float4(0.f, 0.f, 0.f, 0.f);
    for (int k = beg + wave; k < end; k += 4) {
        const int i = list[k];
        const float4* tp = patches4 + (size_t)i * D4;
        float4 a = tp[lane];
        float4 b = tp[lane + P4];
        float4 c = tp[lane + 2 * P4];
        float4 xb;
        xb.x = (a.x + b.x + c.x) * (1.0f / 3.0f);
        xb.y = (a.y + b.y + c.y) * (1.0f / 3.0f);
        xb.z = (a.z + b.z + c.z) * (1.0f / 3.0f);
        xb.w = (a.w + b.w + c.w) * (1.0f / 3.0f);
        s1.x += xb.x; s1.y += xb.y; s1.z += xb.z; s1.w += xb.w;
        s2.x += xb.x * xb.x; s2.y += xb.y * xb.y;
        s2.z += xb.z * xb.z; s2.w += xb.w * xb.w;
    }

    // cross-wave reduce through LDS (float4 stores: conflict-free)
    __shared__ float4 l14[4][64];
    __shared__ float4 l24[4][64];
    l14[wave][lane] = s1;
    l24[wave][lane] = s2;
    __syncthreads();

    const float* l1f = (const float*)l14;
    const float* l2f = (const float*)l24;
    const int t = threadIdx.x;                    // p index 0..255
    float S1 = l1f[t] + l1f[256 + t] + l1f[512 + t] + l1f[768 + t];
    float S2 = l2f[t] + l2f[256 + t] + l2f[512 + t] + l2f[768 + t];

    const float cnt = (float)(end - beg);
    const float nn  = n_old[g] + cnt;
    const float ng  = fmaxf(nn, 1.0f);
    const int   j   = g * P2 + t;
    const float mo  = mean_old[j];
    const float mn  = mo + (S1 - cnt * mo) / ng;
    const float m2n = m2_old[j] + (S2 - (mo + mn) * S1 + cnt * mo * mn);
    const float var = (nn < 2.0f) ? 1.0f : (m2n / ng);
    mean_new[j] = mn;
    inv_std[j]  = 1.0f / (sqrtf(var) + EPSF);
}

// ---- kernel C: normalize ----------------------------------------------------
// 192 threads (3 waves) per token; thread t handles float4 chunk t.
__global__ void k_norm(const float4* __restrict__ patches4,
                       const int* __restrict__ pf,
                       const float4* __restrict__ mean_new4,
                       const float4* __restrict__ inv_std4,
                       float4* __restrict__ out4) {
    const int i = blockIdx.x;
    const int t = threadIdx.x;                    // 0..191
    const int p4 = t & 63;
    const int g = pf[i];
    const float wv = (g >= 0) ? 1.0f : 0.0f;
    const int gg = (g >= 0) ? g : 0;

    float4 x = patches4[(size_t)i * D4 + t];
    float4 m = mean_new4[gg * P4 + p4];
    float4 s = inv_std4[gg * P4 + p4];
    float4 o;
    o.x = (x.x - m.x) * s.x * wv;
    o.y = (x.y - m.y) * s.y * wv;
    o.z = (x.z - m.z) * s.z * wv;
    o.w = (x.w - m.w) * s.w * wv;
    out4[(size_t)i * D4 + t] = o;
}

extern "C" void kernel_launch(void* const* d_in, const int* in_sizes, int n_in,
                              void* d_out, int out_size, void* d_ws, size_t ws_size,
                              hipStream_t stream) {
    const float* patches = (const float*)d_in[0];
    const int*   pos_h   = (const int*)d_in[1];
    const int*   pos_w   = (const int*)d_in[2];
    const int*   mask    = (const int*)d_in[3];
    const float* n_old   = (const float*)d_in[4];
    const float* mean    = (const float*)d_in[5];
    const float* m2      = (const float*)d_in[6];
    float* out = (float*)d_out;

    const int N    = in_sizes[1];   // 32768 tokens
    const int HW   = in_sizes[4];   // 1024 grid cells
    const int HWP2 = in_sizes[5];   // 262144

    // workspace layout:
    //   int  cnt[HW], fill[HW]          <- zeroed each call
    //   int  offs[HW+1], pf[N], list[N]
    //   f32  mean_new[HWP2], inv_std[HWP2]
    int* cnt  = (int*)d_ws;
    int* fill = cnt + HW;
    int* offs = fill + HW;
    int* pf   = offs + (HW + 1);
    int* list = pf + N;
    float* mean_new = (float*)(list + N);
    float* inv_std  = mean_new + HWP2;

    k_zero_cnt<<<(2 * HW + 255) / 256, 256, 0, stream>>>(cnt, 2 * HW);
    k_count<<<(N + 255) / 256, 256, 0, stream>>>(pos_h, pos_w, mask, pf, cnt, N);
    k_scan<<<1, 1024, 0, stream>>>(cnt, offs, HW);
    k_fill<<<(N + 255) / 256, 256, 0, stream>>>(pf, offs, fill, list, N);
    k_moments<<<HW, 256, 0, stream>>>((const float4*)patches, list, offs,
                                      n_old, mean, m2, mean_new, inv_std);
    k_norm<<<N, 192, 0, stream>>>((const float4*)patches, pf,
                                  (const float4*)mean_new, (const float4*)inv_std,
                                  (float4*)out);
}